// Round 17
// baseline (5834.679 us; speedup 1.0000x reference)
//
#include <hip/hip_runtime.h>
#include <hip/hip_bf16.h>
#include <cmath>

#define T_LEN 2048
#define E_DIM 512
#define H_DIM 1024
#define G_DIM 4096   // 4*H
#define V_DIM 32000
#define LSTM_NB 256  // persistent blocks (1 per CU)
#define FCONV_NB 512 // co-resident fcw-convert blocks appended to lstm grid
#define NREP 8       // handoff replicas (spread poll load over 8x lines)
#define RING 4       // handoff ring depth (skew between blocks is <= 1 step)

typedef unsigned short ushortx8 __attribute__((ext_vector_type(8)));
typedef unsigned short ushortx4 __attribute__((ext_vector_type(4)));
typedef short shortx8 __attribute__((ext_vector_type(8)));
typedef float floatx4 __attribute__((ext_vector_type(4)));
typedef unsigned uintx4 __attribute__((ext_vector_type(4)));

__device__ __forceinline__ float bf2f(unsigned short u) {
    return __uint_as_float(((unsigned)u) << 16);
}
__device__ __forceinline__ unsigned short f2bf(float f) {
    __hip_bfloat16 b = __float2bfloat16(f);
    return *reinterpret_cast<unsigned short*>(&b);
}
__device__ __forceinline__ float fast_sigmoid(float x) {
    return 1.f / (1.f + __expf(-x));
}
__device__ __forceinline__ float fast_tanh(float x) {
    return 1.f - 2.f / (__expf(2.f * x) + 1.f);
}

// ---------------------------------------------------------------------------
// Kernel PRE: merged prep (one launch, block-range dispatch):
//   blocks [0, 8000)        : emb (V x E fp32) -> embb bf16
//   blocks [8000, 10048)    : Wi (E x 4H fp32) -> wiT (4H x E bf16) transpose
//   blocks [10048, 10304)   : Wh -> whTp (4H x H bf16), lane-permuted
// ---------------------------------------------------------------------------
#define PRE_EMB_NB   8000
#define PRE_WI_NB    2048
#define PRE_WH_NB    256
__global__ __launch_bounds__(256) void preconv_kernel(const float* __restrict__ emb,
                                                      unsigned short* __restrict__ embb,
                                                      const float* __restrict__ Wi,
                                                      unsigned short* __restrict__ wiT,
                                                      const float* __restrict__ Wh,
                                                      unsigned short* __restrict__ whTp)
{
    __shared__ float tile[32][33];
    const int bid = blockIdx.x;
    const int tid = threadIdx.x;

    if (bid < PRE_EMB_NB) {
        const size_t i = ((size_t)bid * 256 + tid) * 8;
        float4 a = *reinterpret_cast<const float4*>(emb + i);
        float4 b = *reinterpret_cast<const float4*>(emb + i + 4);
        ushortx8 o;
        o[0] = f2bf(a.x); o[1] = f2bf(a.y); o[2] = f2bf(a.z); o[3] = f2bf(a.w);
        o[4] = f2bf(b.x); o[5] = f2bf(b.y); o[6] = f2bf(b.z); o[7] = f2bf(b.w);
        *reinterpret_cast<ushortx8*>(embb + i) = o;
    } else if (bid < PRE_EMB_NB + PRE_WI_NB) {
        const int b2 = bid - PRE_EMB_NB;
        const int nb = (b2 & 127) * 32;   // gate-col tile (4096/32 = 128)
        const int kb = (b2 >> 7) * 32;    // k tile (512/32 = 16)
        const int tx = tid & 31;
        const int ty = tid >> 5;          // 0..7
        #pragma unroll
        for (int i = 0; i < 32; i += 8)
            tile[ty + i][tx] = Wi[(size_t)(kb + ty + i) * G_DIM + nb + tx];
        __syncthreads();
        #pragma unroll
        for (int i = 0; i < 32; i += 8)
            wiT[(size_t)(nb + ty + i) * E_DIM + kb + tx] = f2bf(tile[tx][ty + i]);
    } else {
        const int b3 = bid - PRE_EMB_NB - PRE_WI_NB;
        const int c0 = b3 * 16;
        const int cc = tid & 15;
        const int kk = tid >> 4;
        const int col = c0 + cc;
        unsigned short* dst = whTp + (size_t)col * H_DIM;
        #pragma unroll 4
        for (int r = 0; r < 64; ++r) {
            const int i = r * 16 + kk;
            float v = Wh[(size_t)i * G_DIM + col];
            const int pos = ((i & 255) >> 2) * 16 + (i >> 8) * 4 + (i & 3);
            dst[pos] = f2bf(v);
        }
    }
}

// ---------------------------------------------------------------------------
// Kernel A: xg = gather(embb, sent) @ wiT^T + bi + bh  via bf16 MFMA.
// Output layout GATE-CONTIGUOUS: xg2[t][hidx][gate] (T x 1024 x 4 bf16).
// ---------------------------------------------------------------------------
__global__ __launch_bounds__(256) void xg_mfma_kernel(const int* __restrict__ sent,
                                                      const unsigned short* __restrict__ embb,
                                                      const unsigned short* __restrict__ wiT,
                                                      const float* __restrict__ bi,
                                                      const float* __restrict__ bh,
                                                      unsigned short* __restrict__ xg2)
{
    const int tid  = threadIdx.x;
    const int w    = tid >> 6;
    const int lane = tid & 63;
    const int n0 = blockIdx.x * 64;
    const int m0 = blockIdx.y * 128;
    const int lrow = lane & 15;
    const int lk   = (lane >> 4) * 8;

    const int r0 = sent[m0 + w * 32 + lrow];
    const int r1 = sent[m0 + w * 32 + 16 + lrow];

    floatx4 acc[2][4] = {};
    const unsigned short* a0p = embb + (size_t)r0 * E_DIM + lk;
    const unsigned short* a1p = embb + (size_t)r1 * E_DIM + lk;
    const unsigned short* b0p = wiT + (size_t)(n0 + lrow) * E_DIM + lk;

    for (int k0 = 0; k0 < E_DIM; k0 += 32) {
        shortx8 a0 = *reinterpret_cast<const shortx8*>(a0p + k0);
        shortx8 a1 = *reinterpret_cast<const shortx8*>(a1p + k0);
        shortx8 b0 = *reinterpret_cast<const shortx8*>(b0p + k0);
        shortx8 b1 = *reinterpret_cast<const shortx8*>(b0p + 16 * E_DIM + k0);
        shortx8 b2 = *reinterpret_cast<const shortx8*>(b0p + 32 * E_DIM + k0);
        shortx8 b3 = *reinterpret_cast<const shortx8*>(b0p + 48 * E_DIM + k0);
        acc[0][0] = __builtin_amdgcn_mfma_f32_16x16x32_bf16(a0, b0, acc[0][0], 0, 0, 0);
        acc[0][1] = __builtin_amdgcn_mfma_f32_16x16x32_bf16(a0, b1, acc[0][1], 0, 0, 0);
        acc[0][2] = __builtin_amdgcn_mfma_f32_16x16x32_bf16(a0, b2, acc[0][2], 0, 0, 0);
        acc[0][3] = __builtin_amdgcn_mfma_f32_16x16x32_bf16(a0, b3, acc[0][3], 0, 0, 0);
        acc[1][0] = __builtin_amdgcn_mfma_f32_16x16x32_bf16(a1, b0, acc[1][0], 0, 0, 0);
        acc[1][1] = __builtin_amdgcn_mfma_f32_16x16x32_bf16(a1, b1, acc[1][1], 0, 0, 0);
        acc[1][2] = __builtin_amdgcn_mfma_f32_16x16x32_bf16(a1, b2, acc[1][2], 0, 0, 0);
        acc[1][3] = __builtin_amdgcn_mfma_f32_16x16x32_bf16(a1, b3, acc[1][3], 0, 0, 0);
    }

    #pragma unroll
    for (int j = 0; j < 4; ++j) {
        const int c = n0 + j * 16 + lrow;     // global gate-col in [0,4096)
        const int hidx = c & 1023;
        const int gate = c >> 10;
        const float bias = bi[c] + bh[c];
        #pragma unroll
        for (int i = 0; i < 2; ++i) {
            #pragma unroll
            for (int reg = 0; reg < 4; ++reg) {
                const int r = m0 + w * 32 + i * 16 + (lane >> 4) * 4 + reg;
                xg2[(size_t)r * G_DIM + hidx * 4 + gate] = f2bf(acc[i][j][reg] + bias);
            }
        }
    }
}

// ---------------------------------------------------------------------------
// Kernel B: persistent LSTM (blocks < LSTM_NB) — EXACT r7 structure (proven
// 4603 us). Blocks >= LSTM_NB are co-resident streaming converters:
// fcw (V x H fp32) -> fcwb bf16 (needed only by the LATER fc kernel), folded
// here so the ~50-80 us of conversion overlaps the 4.6 ms recurrence instead
// of serializing before it. No protocol interaction (separate buffers).
// ---------------------------------------------------------------------------
__global__ __launch_bounds__(256) void lstm_kernel(const unsigned short* __restrict__ xg2,
                                                   const unsigned short* __restrict__ whTp,
                                                   unsigned* __restrict__ ring,
                                                   unsigned short* __restrict__ hb,
                                                   const float* __restrict__ fcw,
                                                   unsigned short* __restrict__ fcwb,
                                                   int T)
{
    const int b    = blockIdx.x;
    const int tid  = threadIdx.x;

    if (b >= LSTM_NB) {
        // ---- co-resident fcw -> bf16 converter, then exit
        const size_t total  = (size_t)V_DIM * H_DIM;
        const size_t stride = (size_t)FCONV_NB * 256 * 8;
        size_t i = ((size_t)(b - LSTM_NB) * 256 + tid) * 8;
        for (; i < total; i += stride) {
            float4 a = *reinterpret_cast<const float4*>(fcw + i);
            float4 v = *reinterpret_cast<const float4*>(fcw + i + 4);
            ushortx8 o;
            o[0] = f2bf(a.x); o[1] = f2bf(a.y); o[2] = f2bf(a.z); o[3] = f2bf(a.w);
            o[4] = f2bf(v.x); o[5] = f2bf(v.y); o[6] = f2bf(v.z); o[7] = f2bf(v.w);
            *reinterpret_cast<ushortx8*>(fcwb + i) = o;
        }
        return;
    }

    const int w    = tid >> 6;
    const int lane = tid & 63;
    const int s    = b * 4;
    const int rep  = b & (NREP - 1);

    __shared__ float h_lds[H_DIM];

    float c_val = 0.0f;   // live in lane 0 of each wave

    for (int t = 0; t < T; ++t) {
        // prefetch this step's 4 gate biases for h-index s+w (lane 0, 8B)
        float xr[4] = {0.f, 0.f, 0.f, 0.f};
        if (lane == 0) {
            ushortx4 xv = *reinterpret_cast<const ushortx4*>(
                xg2 + (size_t)t * G_DIM + (size_t)(s + w) * 4);
            #pragma unroll
            for (int q = 0; q < 4; ++q) xr[q] = bf2f(xv[q]);
        }

        // ---- poll+fetch h_{t-1} from replica `rep` of ring slot (t-1)&3
        if (t) {
            const unsigned* pp = ring + ((t - 1) & (RING - 1)) * (NREP * H_DIM)
                                      + rep * H_DIM + tid * 4;
            const unsigned tg = (unsigned)t;
            uintx4 v;
            int guard = 0;
            bool ok;
            do {
                asm volatile("global_load_dwordx4 %0, %1, off sc0 sc1\n\t"
                             "s_waitcnt vmcnt(0)"
                             : "=&v"(v) : "v"(pp) : "memory");
                ok = ((v[0] >> 16) == tg) & ((v[1] >> 16) == tg)
                   & ((v[2] >> 16) == tg) & ((v[3] >> 16) == tg);
            } while (!ok && ++guard < 8192);
            floatx4 hv;
            hv[0] = __uint_as_float(v[0] << 16);
            hv[1] = __uint_as_float(v[1] << 16);
            hv[2] = __uint_as_float(v[2] << 16);
            hv[3] = __uint_as_float(v[3] << 16);
            *reinterpret_cast<floatx4*>(&h_lds[tid * 4]) = hv;
        } else {
            floatx4 z = {0.f, 0.f, 0.f, 0.f};
            *reinterpret_cast<floatx4*>(&h_lds[tid * 4]) = z;
        }
        __syncthreads();   // h_lds staged (sole barrier per step)

        // ---- h into registers (16/lane, c-interleaved: elem c*256+4*lane+e)
        float hreg[16];
        #pragma unroll
        for (int c = 0; c < 4; ++c) {
            floatx4 hv = *reinterpret_cast<const floatx4*>(&h_lds[c * 256 + lane * 4]);
            hreg[c * 4 + 0] = hv[0]; hreg[c * 4 + 1] = hv[1];
            hreg[c * 4 + 2] = hv[2]; hreg[c * 4 + 3] = hv[3];
        }

        // ---- wave w: 4 gate dots of h-index s+w (rows q*1024 + s + w)
        float sums[4];
        #pragma unroll
        for (int q = 0; q < 4; ++q) {
            const ushortx8* wp = reinterpret_cast<const ushortx8*>(
                whTp + ((size_t)((q << 10) + s + w)) * H_DIM + lane * 16);
            ushortx8 w0 = wp[0];
            ushortx8 w1 = wp[1];
            float sm = 0.f;
            #pragma unroll
            for (int e = 0; e < 8; ++e) sm += bf2f(w0[e]) * hreg[e];
            #pragma unroll
            for (int e = 0; e < 8; ++e) sm += bf2f(w1[e]) * hreg[8 + e];
            #pragma unroll
            for (int off = 32; off; off >>= 1) sm += __shfl_xor(sm, off, 64);
            sums[q] = sm;
        }

        // ---- lane 0: gates, state update, 8 replica stores + hb store
        if (lane == 0) {
            float ig = fast_sigmoid(sums[0] + xr[0]);
            float fg = fast_sigmoid(sums[1] + xr[1]);
            float gg = fast_tanh(sums[2] + xr[2]);
            float og = fast_sigmoid(sums[3] + xr[3]);
            c_val = fg * c_val + ig * gg;
            float h = og * fast_tanh(c_val);
            const unsigned short hbf = f2bf(h);
            const unsigned pk = ((unsigned)(t + 1) << 16) | (unsigned)hbf;
            unsigned* base = ring + (t & (RING - 1)) * (NREP * H_DIM) + s + w;
            #pragma unroll
            for (int r = 0; r < NREP; ++r) {
                unsigned* sp = base + r * H_DIM;
                asm volatile("global_store_dword %0, %1, off sc0 sc1"
                             :: "v"(sp), "v"(pk) : "memory");
            }
            hb[(size_t)t * H_DIM + s + w] = hbf;   // cached; for fc kernel
        }
        // no trailing barrier: next-step h_lds writes are data-dependent on
        // the poll, which requires all blocks' current-step stores.
    }
}

// ---------------------------------------------------------------------------
// Kernel C: logits = relu(hb @ fcwb^T + fc_b) -> d_out via bf16 MFMA.
// Tile 256(M) x 128(N) (r16-proven). Wave w owns rows w*64..+64; acc[4][8].
// ---------------------------------------------------------------------------
__global__ __launch_bounds__(256) void fc_kernel(const unsigned short* __restrict__ hb,
                                                 const unsigned short* __restrict__ fcwb,
                                                 const float* __restrict__ fcb,
                                                 float* __restrict__ out)
{
    const int tid  = threadIdx.x;
    const int w    = tid >> 6;
    const int lane = tid & 63;
    const int n0 = blockIdx.x * 128;
    const int m0 = blockIdx.y * 256;
    const int lrow = lane & 15;
    const int lk   = (lane >> 4) * 8;

    floatx4 acc[4][8] = {};
    const unsigned short* ap = hb + (size_t)(m0 + w * 64 + lrow) * H_DIM + lk;
    const unsigned short* b0p = fcwb + (size_t)(n0 + lrow) * H_DIM + lk;

    for (int k0 = 0; k0 < H_DIM; k0 += 32) {
        shortx8 a0 = *reinterpret_cast<const shortx8*>(ap + k0);
        shortx8 a1 = *reinterpret_cast<const shortx8*>(ap + 16 * H_DIM + k0);
        shortx8 a2 = *reinterpret_cast<const shortx8*>(ap + 32 * H_DIM + k0);
        shortx8 a3 = *reinterpret_cast<const shortx8*>(ap + 48 * H_DIM + k0);
        #pragma unroll
        for (int j = 0; j < 8; ++j) {
            shortx8 bj = *reinterpret_cast<const shortx8*>(b0p + j * 16 * H_DIM + k0);
            acc[0][j] = __builtin_amdgcn_mfma_f32_16x16x32_bf16(a0, bj, acc[0][j], 0, 0, 0);
            acc[1][j] = __builtin_amdgcn_mfma_f32_16x16x32_bf16(a1, bj, acc[1][j], 0, 0, 0);
            acc[2][j] = __builtin_amdgcn_mfma_f32_16x16x32_bf16(a2, bj, acc[2][j], 0, 0, 0);
            acc[3][j] = __builtin_amdgcn_mfma_f32_16x16x32_bf16(a3, bj, acc[3][j], 0, 0, 0);
        }
    }

    #pragma unroll
    for (int j = 0; j < 8; ++j) {
        const int c = n0 + j * 16 + lrow;
        const float bias = fcb[c];
        #pragma unroll
        for (int i = 0; i < 4; ++i) {
            #pragma unroll
            for (int reg = 0; reg < 4; ++reg) {
                const int r = m0 + w * 64 + i * 16 + (lane >> 4) * 4 + reg;
                out[(size_t)r * V_DIM + c] = fmaxf(acc[i][j][reg] + bias, 0.f);
            }
        }
    }
}

// ---------------------------------------------------------------------------
// Kernel D: in-place row log-softmax on d_out (online max/sum, 2 passes).
// ---------------------------------------------------------------------------
__global__ __launch_bounds__(256) void lsm_kernel(float* __restrict__ out)
{
    const int row = blockIdx.x;
    float* p = out + (size_t)row * V_DIM;
    const int tid = threadIdx.x;
    __shared__ float ms[256], ss[256];

    float m = -1e30f, sacc = 0.f;
    for (int i4 = tid; i4 < V_DIM / 4; i4 += 256) {
        float4 v = *reinterpret_cast<const float4*>(p + i4 * 4);
        float vm = fmaxf(fmaxf(v.x, v.y), fmaxf(v.z, v.w));
        if (vm > m) { sacc *= __expf(m - vm); m = vm; }
        sacc += __expf(v.x - m) + __expf(v.y - m) + __expf(v.z - m) + __expf(v.w - m);
    }
    ms[tid] = m; ss[tid] = sacc; __syncthreads();
    for (int sft = 128; sft; sft >>= 1) {
        if (tid < sft) {
            float m2 = ms[tid + sft], s2 = ss[tid + sft];
            float mm = fmaxf(ms[tid], m2);
            ss[tid] = ss[tid] * __expf(ms[tid] - mm) + s2 * __expf(m2 - mm);
            ms[tid] = mm;
        }
        __syncthreads();
    }
    const float L = ms[0] + logf(ss[0]);

    for (int i4 = tid; i4 < V_DIM / 4; i4 += 256) {
        float4 v = *reinterpret_cast<const float4*>(p + i4 * 4);
        v.x -= L; v.y -= L; v.z -= L; v.w -= L;
        *reinterpret_cast<float4*>(p + i4 * 4) = v;
    }
}

// ---------------------------------------------------------------------------
extern "C" void kernel_launch(void* const* d_in, const int* in_sizes, int n_in,
                              void* d_out, int out_size, void* d_ws, size_t ws_size,
                              hipStream_t stream)
{
    const int*   sent = (const int*)  d_in[0];
    const float* emb  = (const float*)d_in[1];
    const float* Wi   = (const float*)d_in[2];
    const float* Wh   = (const float*)d_in[3];
    const float* bi   = (const float*)d_in[4];
    const float* bh   = (const float*)d_in[5];
    const float* fcw  = (const float*)d_in[6];
    const float* fcb  = (const float*)d_in[7];
    float* out = (float*)d_out;

    uint8_t* ws = (uint8_t*)d_ws;
    size_t off = 0;
    unsigned*       ring = (unsigned*)(ws + off);       off += (size_t)RING * NREP * H_DIM * 4; // 128 KiB
    unsigned short* xg2  = (unsigned short*)(ws + off); off += (size_t)T_LEN * G_DIM * 2;  // 16.8 MB
    unsigned short* whTp = (unsigned short*)(ws + off); off += (size_t)G_DIM * H_DIM * 2;  //  8.4 MB
    unsigned short* hb   = (unsigned short*)(ws + off); off += (size_t)T_LEN * H_DIM * 2;  //  4.2 MB
    // overlay region: embb+wiT live only until xg_mfma; fcwb (larger) reuses it
    uint8_t* R = ws + off;
    unsigned short* fcwb = (unsigned short*)R;                                   // 65.5 MB
    unsigned short* embb = (unsigned short*)R;                                   // 32.8 MB
    unsigned short* wiT  = (unsigned short*)(R + (size_t)V_DIM * E_DIM * 2);     //  4.2 MB

    hipMemsetAsync(ring, 0, (size_t)RING * NREP * H_DIM * 4, stream);
    preconv_kernel<<<PRE_EMB_NB + PRE_WI_NB + PRE_WH_NB, 256, 0, stream>>>(
        emb, embb, Wi, wiT, Wh, whTp);
    xg_mfma_kernel<<<dim3(G_DIM / 64, T_LEN / 128), 256, 0, stream>>>(sent, embb, wiT, bi, bh, xg2);
    // fcw conversion is folded into the lstm dispatch (blocks >= LSTM_NB);
    // it overwrites embb/wiT, which are dead after xg_mfma.
    lstm_kernel<<<LSTM_NB + FCONV_NB, 256, 0, stream>>>(xg2, whTp, ring, hb, fcw, fcwb, T_LEN);
    fc_kernel<<<dim3(V_DIM / 128, T_LEN / 256), 256, 0, stream>>>(hb, fcwb, fcb, out);
    lsm_kernel<<<T_LEN, 256, 0, stream>>>(out);
}

// Round 18
// 5214.715 us; speedup vs baseline: 1.1189x; 1.1189x over previous
//
#include <hip/hip_runtime.h>
#include <hip/hip_bf16.h>
#include <cmath>

#define T_LEN 2048
#define E_DIM 512
#define H_DIM 1024
#define G_DIM 4096   // 4*H
#define V_DIM 32000
#define LSTM_NB 256  // persistent blocks (1 per CU)
#define NREP 8       // handoff replicas (spread poll load over 8x lines)
#define RING 4       // handoff ring depth (skew between blocks is <= 1 step)

typedef unsigned short ushortx8 __attribute__((ext_vector_type(8)));
typedef unsigned short ushortx4 __attribute__((ext_vector_type(4)));
typedef short shortx8 __attribute__((ext_vector_type(8)));
typedef float floatx4 __attribute__((ext_vector_type(4)));
typedef unsigned uintx4 __attribute__((ext_vector_type(4)));

__device__ __forceinline__ float bf2f(unsigned short u) {
    return __uint_as_float(((unsigned)u) << 16);
}
__device__ __forceinline__ unsigned short f2bf(float f) {
    __hip_bfloat16 b = __float2bfloat16(f);
    return *reinterpret_cast<unsigned short*>(&b);
}
__device__ __forceinline__ float fast_sigmoid(float x) {
    return 1.f / (1.f + __expf(-x));
}
__device__ __forceinline__ float fast_tanh(float x) {
    return 1.f - 2.f / (__expf(2.f * x) + 1.f);
}

// ---------------------------------------------------------------------------
// Kernel PRE: merged prep (one launch, block-range dispatch; all strictly
// BEFORE the lstm — r17 proved concurrent traffic perturbs the recurrence):
//   blocks [0, 8000)        : emb (V x E fp32) -> embb bf16
//   blocks [8000, 10048)    : Wi (E x 4H fp32) -> wiT (4H x E bf16) transpose
//   blocks [10048, 10304)   : Wh -> whTp (4H x H bf16), lane-permuted
// ---------------------------------------------------------------------------
#define PRE_EMB_NB   8000
#define PRE_WI_NB    2048
#define PRE_WH_NB    256
__global__ __launch_bounds__(256) void preconv_kernel(const float* __restrict__ emb,
                                                      unsigned short* __restrict__ embb,
                                                      const float* __restrict__ Wi,
                                                      unsigned short* __restrict__ wiT,
                                                      const float* __restrict__ Wh,
                                                      unsigned short* __restrict__ whTp)
{
    __shared__ float tile[32][33];
    const int bid = blockIdx.x;
    const int tid = threadIdx.x;

    if (bid < PRE_EMB_NB) {
        const size_t i = ((size_t)bid * 256 + tid) * 8;
        float4 a = *reinterpret_cast<const float4*>(emb + i);
        float4 b = *reinterpret_cast<const float4*>(emb + i + 4);
        ushortx8 o;
        o[0] = f2bf(a.x); o[1] = f2bf(a.y); o[2] = f2bf(a.z); o[3] = f2bf(a.w);
        o[4] = f2bf(b.x); o[5] = f2bf(b.y); o[6] = f2bf(b.z); o[7] = f2bf(b.w);
        *reinterpret_cast<ushortx8*>(embb + i) = o;
    } else if (bid < PRE_EMB_NB + PRE_WI_NB) {
        const int b2 = bid - PRE_EMB_NB;
        const int nb = (b2 & 127) * 32;   // gate-col tile (4096/32 = 128)
        const int kb = (b2 >> 7) * 32;    // k tile (512/32 = 16)
        const int tx = tid & 31;
        const int ty = tid >> 5;          // 0..7
        #pragma unroll
        for (int i = 0; i < 32; i += 8)
            tile[ty + i][tx] = Wi[(size_t)(kb + ty + i) * G_DIM + nb + tx];
        __syncthreads();
        #pragma unroll
        for (int i = 0; i < 32; i += 8)
            wiT[(size_t)(nb + ty + i) * E_DIM + kb + tx] = f2bf(tile[tx][ty + i]);
    } else {
        const int b3 = bid - PRE_EMB_NB - PRE_WI_NB;
        const int c0 = b3 * 16;
        const int cc = tid & 15;
        const int kk = tid >> 4;
        const int col = c0 + cc;
        unsigned short* dst = whTp + (size_t)col * H_DIM;
        #pragma unroll 4
        for (int r = 0; r < 64; ++r) {
            const int i = r * 16 + kk;
            float v = Wh[(size_t)i * G_DIM + col];
            const int pos = ((i & 255) >> 2) * 16 + (i >> 8) * 4 + (i & 3);
            dst[pos] = f2bf(v);
        }
    }
}

// ---------------------------------------------------------------------------
// Kernel F: fc_w (V x H fp32) -> bf16 copy. Serial, BEFORE the lstm (r16
// placement — r17 proved folding it into the lstm window costs 620 us).
// ---------------------------------------------------------------------------
__global__ __launch_bounds__(256) void fcwconv_kernel(const float* __restrict__ src,
                                                      unsigned short* __restrict__ dst)
{
    const size_t i = ((size_t)blockIdx.x * 256 + threadIdx.x) * 8;
    float4 a = *reinterpret_cast<const float4*>(src + i);
    float4 b = *reinterpret_cast<const float4*>(src + i + 4);
    ushortx8 o;
    o[0] = f2bf(a.x); o[1] = f2bf(a.y); o[2] = f2bf(a.z); o[3] = f2bf(a.w);
    o[4] = f2bf(b.x); o[5] = f2bf(b.y); o[6] = f2bf(b.z); o[7] = f2bf(b.w);
    *reinterpret_cast<ushortx8*>(dst + i) = o;
}

// ---------------------------------------------------------------------------
// Kernel A: xg = gather(embb, sent) @ wiT^T + bi + bh  via bf16 MFMA.
// Output layout GATE-CONTIGUOUS: xg2[t][hidx][gate] (T x 1024 x 4 bf16).
// ---------------------------------------------------------------------------
__global__ __launch_bounds__(256) void xg_mfma_kernel(const int* __restrict__ sent,
                                                      const unsigned short* __restrict__ embb,
                                                      const unsigned short* __restrict__ wiT,
                                                      const float* __restrict__ bi,
                                                      const float* __restrict__ bh,
                                                      unsigned short* __restrict__ xg2)
{
    const int tid  = threadIdx.x;
    const int w    = tid >> 6;
    const int lane = tid & 63;
    const int n0 = blockIdx.x * 64;
    const int m0 = blockIdx.y * 128;
    const int lrow = lane & 15;
    const int lk   = (lane >> 4) * 8;

    const int r0 = sent[m0 + w * 32 + lrow];
    const int r1 = sent[m0 + w * 32 + 16 + lrow];

    floatx4 acc[2][4] = {};
    const unsigned short* a0p = embb + (size_t)r0 * E_DIM + lk;
    const unsigned short* a1p = embb + (size_t)r1 * E_DIM + lk;
    const unsigned short* b0p = wiT + (size_t)(n0 + lrow) * E_DIM + lk;

    for (int k0 = 0; k0 < E_DIM; k0 += 32) {
        shortx8 a0 = *reinterpret_cast<const shortx8*>(a0p + k0);
        shortx8 a1 = *reinterpret_cast<const shortx8*>(a1p + k0);
        shortx8 b0 = *reinterpret_cast<const shortx8*>(b0p + k0);
        shortx8 b1 = *reinterpret_cast<const shortx8*>(b0p + 16 * E_DIM + k0);
        shortx8 b2 = *reinterpret_cast<const shortx8*>(b0p + 32 * E_DIM + k0);
        shortx8 b3 = *reinterpret_cast<const shortx8*>(b0p + 48 * E_DIM + k0);
        acc[0][0] = __builtin_amdgcn_mfma_f32_16x16x32_bf16(a0, b0, acc[0][0], 0, 0, 0);
        acc[0][1] = __builtin_amdgcn_mfma_f32_16x16x32_bf16(a0, b1, acc[0][1], 0, 0, 0);
        acc[0][2] = __builtin_amdgcn_mfma_f32_16x16x32_bf16(a0, b2, acc[0][2], 0, 0, 0);
        acc[0][3] = __builtin_amdgcn_mfma_f32_16x16x32_bf16(a0, b3, acc[0][3], 0, 0, 0);
        acc[1][0] = __builtin_amdgcn_mfma_f32_16x16x32_bf16(a1, b0, acc[1][0], 0, 0, 0);
        acc[1][1] = __builtin_amdgcn_mfma_f32_16x16x32_bf16(a1, b1, acc[1][1], 0, 0, 0);
        acc[1][2] = __builtin_amdgcn_mfma_f32_16x16x32_bf16(a1, b2, acc[1][2], 0, 0, 0);
        acc[1][3] = __builtin_amdgcn_mfma_f32_16x16x32_bf16(a1, b3, acc[1][3], 0, 0, 0);
    }

    #pragma unroll
    for (int j = 0; j < 4; ++j) {
        const int c = n0 + j * 16 + lrow;     // global gate-col in [0,4096)
        const int hidx = c & 1023;
        const int gate = c >> 10;
        const float bias = bi[c] + bh[c];
        #pragma unroll
        for (int i = 0; i < 2; ++i) {
            #pragma unroll
            for (int reg = 0; reg < 4; ++reg) {
                const int r = m0 + w * 32 + i * 16 + (lane >> 4) * 4 + reg;
                xg2[(size_t)r * G_DIM + hidx * 4 + gate] = f2bf(acc[i][j][reg] + bias);
            }
        }
    }
}

// ---------------------------------------------------------------------------
// Kernel B: persistent LSTM — EXACT r7 structure (proven 4603 us). 256 blocks
// x 256 threads; block b owns h-indices 4b..4b+3; wave w computes the 4 gate
// dots of h-index 4b+w. Handoff: ring[t&3][rep][i] = (tag=t+1)<<16 | bf16(h),
// 8 replica write-through dword stores = data+signal; consumer block b polls
// replica b&7 with ONE single-outstanding dwordx4 sc0 sc1 load per sweep.
// One __syncthreads per step. Bounded spin; ring memset per launch.
// NOTHING ELSE runs concurrently (r17 proved concurrent traffic costs 620us).
// ---------------------------------------------------------------------------
__global__ __launch_bounds__(256) void lstm_kernel(const unsigned short* __restrict__ xg2,
                                                   const unsigned short* __restrict__ whTp,
                                                   unsigned* __restrict__ ring,
                                                   unsigned short* __restrict__ hb,
                                                   int T)
{
    const int b    = blockIdx.x;
    const int tid  = threadIdx.x;
    const int w    = tid >> 6;
    const int lane = tid & 63;
    const int s    = b * 4;
    const int rep  = b & (NREP - 1);

    __shared__ float h_lds[H_DIM];

    float c_val = 0.0f;   // live in lane 0 of each wave

    for (int t = 0; t < T; ++t) {
        // prefetch this step's 4 gate biases for h-index s+w (lane 0, 8B)
        float xr[4] = {0.f, 0.f, 0.f, 0.f};
        if (lane == 0) {
            ushortx4 xv = *reinterpret_cast<const ushortx4*>(
                xg2 + (size_t)t * G_DIM + (size_t)(s + w) * 4);
            #pragma unroll
            for (int q = 0; q < 4; ++q) xr[q] = bf2f(xv[q]);
        }

        // ---- poll+fetch h_{t-1} from replica `rep` of ring slot (t-1)&3
        if (t) {
            const unsigned* pp = ring + ((t - 1) & (RING - 1)) * (NREP * H_DIM)
                                      + rep * H_DIM + tid * 4;
            const unsigned tg = (unsigned)t;
            uintx4 v;
            int guard = 0;
            bool ok;
            do {
                asm volatile("global_load_dwordx4 %0, %1, off sc0 sc1\n\t"
                             "s_waitcnt vmcnt(0)"
                             : "=&v"(v) : "v"(pp) : "memory");
                ok = ((v[0] >> 16) == tg) & ((v[1] >> 16) == tg)
                   & ((v[2] >> 16) == tg) & ((v[3] >> 16) == tg);
            } while (!ok && ++guard < 8192);
            floatx4 hv;
            hv[0] = __uint_as_float(v[0] << 16);
            hv[1] = __uint_as_float(v[1] << 16);
            hv[2] = __uint_as_float(v[2] << 16);
            hv[3] = __uint_as_float(v[3] << 16);
            *reinterpret_cast<floatx4*>(&h_lds[tid * 4]) = hv;
        } else {
            floatx4 z = {0.f, 0.f, 0.f, 0.f};
            *reinterpret_cast<floatx4*>(&h_lds[tid * 4]) = z;
        }
        __syncthreads();   // h_lds staged (sole barrier per step)

        // ---- h into registers (16/lane, c-interleaved: elem c*256+4*lane+e)
        float hreg[16];
        #pragma unroll
        for (int c = 0; c < 4; ++c) {
            floatx4 hv = *reinterpret_cast<const floatx4*>(&h_lds[c * 256 + lane * 4]);
            hreg[c * 4 + 0] = hv[0]; hreg[c * 4 + 1] = hv[1];
            hreg[c * 4 + 2] = hv[2]; hreg[c * 4 + 3] = hv[3];
        }

        // ---- wave w: 4 gate dots of h-index s+w (rows q*1024 + s + w)
        float sums[4];
        #pragma unroll
        for (int q = 0; q < 4; ++q) {
            const ushortx8* wp = reinterpret_cast<const ushortx8*>(
                whTp + ((size_t)((q << 10) + s + w)) * H_DIM + lane * 16);
            ushortx8 w0 = wp[0];
            ushortx8 w1 = wp[1];
            float sm = 0.f;
            #pragma unroll
            for (int e = 0; e < 8; ++e) sm += bf2f(w0[e]) * hreg[e];
            #pragma unroll
            for (int e = 0; e < 8; ++e) sm += bf2f(w1[e]) * hreg[8 + e];
            #pragma unroll
            for (int off = 32; off; off >>= 1) sm += __shfl_xor(sm, off, 64);
            sums[q] = sm;
        }

        // ---- lane 0: gates, state update, 8 replica stores + hb store
        if (lane == 0) {
            float ig = fast_sigmoid(sums[0] + xr[0]);
            float fg = fast_sigmoid(sums[1] + xr[1]);
            float gg = fast_tanh(sums[2] + xr[2]);
            float og = fast_sigmoid(sums[3] + xr[3]);
            c_val = fg * c_val + ig * gg;
            float h = og * fast_tanh(c_val);
            const unsigned short hbf = f2bf(h);
            const unsigned pk = ((unsigned)(t + 1) << 16) | (unsigned)hbf;
            unsigned* base = ring + (t & (RING - 1)) * (NREP * H_DIM) + s + w;
            #pragma unroll
            for (int r = 0; r < NREP; ++r) {
                unsigned* sp = base + r * H_DIM;
                asm volatile("global_store_dword %0, %1, off sc0 sc1"
                             :: "v"(sp), "v"(pk) : "memory");
            }
            hb[(size_t)t * H_DIM + s + w] = hbf;   // cached; for fc kernel
        }
        // no trailing barrier: next-step h_lds writes are data-dependent on
        // the poll, which requires all blocks' current-step stores.
    }
}

// ---------------------------------------------------------------------------
// Kernel C: logits = relu(hb @ fcwb^T + fc_b) -> d_out via bf16 MFMA.
// Tile 256(M) x 128(N) (r16-proven). Wave w owns rows w*64..+64; acc[4][8].
// ---------------------------------------------------------------------------
__global__ __launch_bounds__(256) void fc_kernel(const unsigned short* __restrict__ hb,
                                                 const unsigned short* __restrict__ fcwb,
                                                 const float* __restrict__ fcb,
                                                 float* __restrict__ out)
{
    const int tid  = threadIdx.x;
    const int w    = tid >> 6;
    const int lane = tid & 63;
    const int n0 = blockIdx.x * 128;
    const int m0 = blockIdx.y * 256;
    const int lrow = lane & 15;
    const int lk   = (lane >> 4) * 8;

    floatx4 acc[4][8] = {};
    const unsigned short* ap = hb + (size_t)(m0 + w * 64 + lrow) * H_DIM + lk;
    const unsigned short* b0p = fcwb + (size_t)(n0 + lrow) * H_DIM + lk;

    for (int k0 = 0; k0 < H_DIM; k0 += 32) {
        shortx8 a0 = *reinterpret_cast<const shortx8*>(ap + k0);
        shortx8 a1 = *reinterpret_cast<const shortx8*>(ap + 16 * H_DIM + k0);
        shortx8 a2 = *reinterpret_cast<const shortx8*>(ap + 32 * H_DIM + k0);
        shortx8 a3 = *reinterpret_cast<const shortx8*>(ap + 48 * H_DIM + k0);
        #pragma unroll
        for (int j = 0; j < 8; ++j) {
            shortx8 bj = *reinterpret_cast<const shortx8*>(b0p + j * 16 * H_DIM + k0);
            acc[0][j] = __builtin_amdgcn_mfma_f32_16x16x32_bf16(a0, bj, acc[0][j], 0, 0, 0);
            acc[1][j] = __builtin_amdgcn_mfma_f32_16x16x32_bf16(a1, bj, acc[1][j], 0, 0, 0);
            acc[2][j] = __builtin_amdgcn_mfma_f32_16x16x32_bf16(a2, bj, acc[2][j], 0, 0, 0);
            acc[3][j] = __builtin_amdgcn_mfma_f32_16x16x32_bf16(a3, bj, acc[3][j], 0, 0, 0);
        }
    }

    #pragma unroll
    for (int j = 0; j < 8; ++j) {
        const int c = n0 + j * 16 + lrow;
        const float bias = fcb[c];
        #pragma unroll
        for (int i = 0; i < 4; ++i) {
            #pragma unroll
            for (int reg = 0; reg < 4; ++reg) {
                const int r = m0 + w * 64 + i * 16 + (lane >> 4) * 4 + reg;
                out[(size_t)r * V_DIM + c] = fmaxf(acc[i][j][reg] + bias, 0.f);
            }
        }
    }
}

// ---------------------------------------------------------------------------
// Kernel D: in-place row log-softmax on d_out (online max/sum). 1024 threads
// per row: 4x the per-row read bandwidth of the 256-thread version.
// ---------------------------------------------------------------------------
__global__ __launch_bounds__(1024) void lsm_kernel(float* __restrict__ out)
{
    const int row = blockIdx.x;
    float* p = out + (size_t)row * V_DIM;
    const int tid = threadIdx.x;
    __shared__ float ms[1024], ss[1024];

    float m = -1e30f, sacc = 0.f;
    for (int i4 = tid; i4 < V_DIM / 4; i4 += 1024) {
        float4 v = *reinterpret_cast<const float4*>(p + i4 * 4);
        float vm = fmaxf(fmaxf(v.x, v.y), fmaxf(v.z, v.w));
        if (vm > m) { sacc *= __expf(m - vm); m = vm; }
        sacc += __expf(v.x - m) + __expf(v.y - m) + __expf(v.z - m) + __expf(v.w - m);
    }
    ms[tid] = m; ss[tid] = sacc; __syncthreads();
    for (int sft = 512; sft; sft >>= 1) {
        if (tid < sft) {
            float m2 = ms[tid + sft], s2 = ss[tid + sft];
            float mm = fmaxf(ms[tid], m2);
            ss[tid] = ss[tid] * __expf(ms[tid] - mm) + s2 * __expf(m2 - mm);
            ms[tid] = mm;
        }
        __syncthreads();
    }
    const float L = ms[0] + logf(ss[0]);

    for (int i4 = tid; i4 < V_DIM / 4; i4 += 1024) {
        float4 v = *reinterpret_cast<const float4*>(p + i4 * 4);
        v.x -= L; v.y -= L; v.z -= L; v.w -= L;
        *reinterpret_cast<float4*>(p + i4 * 4) = v;
    }
}

// ---------------------------------------------------------------------------
extern "C" void kernel_launch(void* const* d_in, const int* in_sizes, int n_in,
                              void* d_out, int out_size, void* d_ws, size_t ws_size,
                              hipStream_t stream)
{
    const int*   sent = (const int*)  d_in[0];
    const float* emb  = (const float*)d_in[1];
    const float* Wi   = (const float*)d_in[2];
    const float* Wh   = (const float*)d_in[3];
    const float* bi   = (const float*)d_in[4];
    const float* bh   = (const float*)d_in[5];
    const float* fcw  = (const float*)d_in[6];
    const float* fcb  = (const float*)d_in[7];
    float* out = (float*)d_out;

    uint8_t* ws = (uint8_t*)d_ws;
    size_t off = 0;
    unsigned*       ring = (unsigned*)(ws + off);       off += (size_t)RING * NREP * H_DIM * 4; // 128 KiB
    unsigned short* xg2  = (unsigned short*)(ws + off); off += (size_t)T_LEN * G_DIM * 2;  // 16.8 MB
    unsigned short* whTp = (unsigned short*)(ws + off); off += (size_t)G_DIM * H_DIM * 2;  //  8.4 MB
    unsigned short* hb   = (unsigned short*)(ws + off); off += (size_t)T_LEN * H_DIM * 2;  //  4.2 MB
    // overlay region: embb+wiT live only until xg_mfma; fcwb (larger) reuses it
    uint8_t* R = ws + off;
    unsigned short* fcwb = (unsigned short*)R;                                   // 65.5 MB
    unsigned short* embb = (unsigned short*)R;                                   // 32.8 MB
    unsigned short* wiT  = (unsigned short*)(R + (size_t)V_DIM * E_DIM * 2);     //  4.2 MB

    hipMemsetAsync(ring, 0, (size_t)RING * NREP * H_DIM * 4, stream);
    preconv_kernel<<<PRE_EMB_NB + PRE_WI_NB + PRE_WH_NB, 256, 0, stream>>>(
        emb, embb, Wi, wiT, Wh, whTp);
    xg_mfma_kernel<<<dim3(G_DIM / 64, T_LEN / 128), 256, 0, stream>>>(sent, embb, wiT, bi, bh, xg2);
    fcwconv_kernel<<<(int)(((size_t)V_DIM * H_DIM / 8) / 256), 256, 0, stream>>>(fcw, fcwb);  // overwrites embb/wiT (dead)
    lstm_kernel<<<LSTM_NB, 256, 0, stream>>>(xg2, whTp, ring, hb, T_LEN);
    fc_kernel<<<dim3(V_DIM / 128, T_LEN / 256), 256, 0, stream>>>(hb, fcwb, fcb, out);
    lsm_kernel<<<T_LEN, 1024, 0, stream>>>(out);
}